// Round 1
// baseline (21.101 us; speedup 1.0000x reference)
//
#include <hip/hip_runtime.h>
#include <hip/hip_bf16.h>

// Problem constants (from reference)
#define BATCH     4096
#define N_CTX     8
#define N_TGT     16
#define NUM_DOCS  500
#define NUM_WORDS 8000
#define VEC_DIM   128

// ---------------------------------------------------------------------------
// Kernel 1: transpose O (VEC_DIM x NUM_WORDS) -> OT (NUM_WORDS x VEC_DIM)
// so each target word's 128-float vector is contiguous (512 B).
// 8000 % 32 == 0 and 128 % 32 == 0, so no bounds checks needed.
// ---------------------------------------------------------------------------
__global__ __launch_bounds__(256) void transpose_O_kernel(
    const float* __restrict__ O, float* __restrict__ OT) {
  __shared__ float tile[32][33];  // +1 pad: no bank conflicts
  const int wBase = blockIdx.x * 32;  // word dim (cols of O)
  const int vBase = blockIdx.y * 32;  // vec  dim (rows of O)
  const int tx = threadIdx.x;         // 0..31
  const int ty = threadIdx.y;         // 0..7
#pragma unroll
  for (int i = ty; i < 32; i += 8) {
    // coalesced read of O: consecutive tx -> consecutive words
    tile[i][tx] = O[(size_t)(vBase + i) * NUM_WORDS + (wBase + tx)];
  }
  __syncthreads();
#pragma unroll
  for (int i = ty; i < 32; i += 8) {
    // coalesced write of OT: consecutive tx -> consecutive vec components
    OT[(size_t)(wBase + i) * VEC_DIM + (vBase + tx)] = tile[tx][i];
  }
}

// ---------------------------------------------------------------------------
// Kernel 2: fused gather-sum + 16 dot products.
// One wave (64 lanes) per batch element; lane owns components {2*lane, 2*lane+1}.
// OT_MODE=1: read contiguous OT rows. OT_MODE=0: strided fallback from O.
// ---------------------------------------------------------------------------
template <int OT_MODE>
__global__ __launch_bounds__(256) void fused_kernel(
    const int* __restrict__ ctx, const int* __restrict__ docs,
    const int* __restrict__ tgt, const float* __restrict__ D,
    const float* __restrict__ W, const float* __restrict__ Ov,
    float* __restrict__ out) {
  const int wave = threadIdx.x >> 6;
  const int lane = threadIdx.x & 63;
  const int b = blockIdx.x * 4 + wave;
  if (b >= BATCH) return;

  const int doc = docs[b];
  const float* Dbase = D + (size_t)doc * (NUM_WORDS * VEC_DIM);

  // x[v] = sum_c D[doc, ctx[c], v] + W[ctx[c], v]; lane holds v = 2*lane, 2*lane+1
  float2 acc = make_float2(0.f, 0.f);
#pragma unroll
  for (int c = 0; c < N_CTX; ++c) {
    const int wid = ctx[b * N_CTX + c];
    const float2 d = *(const float2*)(Dbase + (size_t)wid * VEC_DIM + 2 * lane);
    const float2 w = *(const float2*)(W + (size_t)wid * VEC_DIM + 2 * lane);
    acc.x += d.x + w.x;
    acc.y += d.y + w.y;
  }

  float res = 0.f;
#pragma unroll
  for (int t = 0; t < N_TGT; ++t) {
    const int wid = tgt[b * N_TGT + t];
    float p;
    if (OT_MODE) {
      const float2 o = *(const float2*)(Ov + (size_t)wid * VEC_DIM + 2 * lane);
      p = acc.x * o.x + acc.y * o.y;
    } else {
      const float o0 = Ov[(size_t)(2 * lane) * NUM_WORDS + wid];
      const float o1 = Ov[(size_t)(2 * lane + 1) * NUM_WORDS + wid];
      p = acc.x * o0 + acc.y * o1;
    }
    // 64-lane butterfly reduction
#pragma unroll
    for (int s = 32; s > 0; s >>= 1) p += __shfl_xor(p, s, 64);
    if (lane == t) res = p;  // park target t's dot on lane t
  }
  if (lane < N_TGT) out[b * N_TGT + lane] = res;  // coalesced 16-wide store
}

extern "C" void kernel_launch(void* const* d_in, const int* in_sizes, int n_in,
                              void* d_out, int out_size, void* d_ws, size_t ws_size,
                              hipStream_t stream) {
  const int*   ctx  = (const int*)d_in[0];    // (4096, 8)
  const int*   docs = (const int*)d_in[1];    // (4096,)
  const int*   tgt  = (const int*)d_in[2];    // (4096, 16)
  const float* D    = (const float*)d_in[3];  // (500, 8000, 128)
  const float* W    = (const float*)d_in[4];  // (8000, 128)
  const float* O    = (const float*)d_in[5];  // (128, 8000)
  float*       out  = (float*)d_out;          // (4096, 16)

  const size_t ot_bytes = (size_t)NUM_WORDS * VEC_DIM * sizeof(float);  // 4 MB
  const dim3 fusedGrid(BATCH / 4);
  const dim3 fusedBlock(256);

  if (ws_size >= ot_bytes) {
    float* OT = (float*)d_ws;
    transpose_O_kernel<<<dim3(NUM_WORDS / 32, VEC_DIM / 32), dim3(32, 8), 0, stream>>>(O, OT);
    fused_kernel<1><<<fusedGrid, fusedBlock, 0, stream>>>(ctx, docs, tgt, D, W, OT, out);
  } else {
    fused_kernel<0><<<fusedGrid, fusedBlock, 0, stream>>>(ctx, docs, tgt, D, W, O, out);
  }
}

// Round 2
// 20.644 us; speedup vs baseline: 1.0222x; 1.0222x over previous
//
#include <hip/hip_runtime.h>
#include <hip/hip_bf16.h>

// Problem constants (from reference)
#define BATCH     4096
#define N_CTX     8
#define N_TGT     16
#define NUM_DOCS  500
#define NUM_WORDS 8000
#define VEC_DIM   128

// ---------------------------------------------------------------------------
// Kernel 1: transpose O (VEC_DIM x NUM_WORDS) -> OT (NUM_WORDS x VEC_DIM)
// so each target word's 128-float vector is contiguous (512 B).
// 8000 % 32 == 0 and 128 % 32 == 0, so no bounds checks needed.
// ---------------------------------------------------------------------------
__global__ __launch_bounds__(256) void transpose_O_kernel(
    const float* __restrict__ O, float* __restrict__ OT) {
  __shared__ float tile[32][33];  // +1 pad: no bank conflicts
  const int wBase = blockIdx.x * 32;  // word dim (cols of O)
  const int vBase = blockIdx.y * 32;  // vec  dim (rows of O)
  const int tx = threadIdx.x;         // 0..31
  const int ty = threadIdx.y;         // 0..7
#pragma unroll
  for (int i = ty; i < 32; i += 8) {
    tile[i][tx] = O[(size_t)(vBase + i) * NUM_WORDS + (wBase + tx)];
  }
  __syncthreads();
#pragma unroll
  for (int i = ty; i < 32; i += 8) {
    OT[(size_t)(wBase + i) * VEC_DIM + (vBase + tx)] = tile[tx][i];
  }
}

// ---------------------------------------------------------------------------
// Kernel 2: fused gather-sum + 16 dot products.
// One wave per batch element; lane owns components {2*lane, 2*lane+1}.
// All index loads + O-row prefetch issued up front (single latency round),
// then D/W accumulate, then a segmented multi-target reduction:
// 16 simultaneous 64-lane sums in 17 shuffles (vs 96 naive).
// ---------------------------------------------------------------------------
__global__ __launch_bounds__(256) void fused_kernel(
    const int* __restrict__ ctx, const int* __restrict__ docs,
    const int* __restrict__ tgt, const float* __restrict__ D,
    const float* __restrict__ W, const float* __restrict__ OT,
    float* __restrict__ out) {
  const int wave = threadIdx.x >> 6;
  const int lane = threadIdx.x & 63;
  const int b = blockIdx.x * 4 + wave;  // grid is exactly BATCH/4 blocks

  // ---- index loads (wave-uniform broadcasts, 16B each) ----
  const int4 c0 = *(const int4*)(ctx + b * N_CTX);
  const int4 c1 = *(const int4*)(ctx + b * N_CTX + 4);
  const int  doc = docs[b];
  const int4 t0 = *(const int4*)(tgt + b * N_TGT);
  const int4 t1 = *(const int4*)(tgt + b * N_TGT + 4);
  const int4 t2 = *(const int4*)(tgt + b * N_TGT + 8);
  const int4 t3 = *(const int4*)(tgt + b * N_TGT + 12);

  const int cw[N_CTX] = {c0.x, c0.y, c0.z, c0.w, c1.x, c1.y, c1.z, c1.w};
  const int tw[N_TGT] = {t0.x, t0.y, t0.z, t0.w, t1.x, t1.y, t1.z, t1.w,
                         t2.x, t2.y, t2.z, t2.w, t3.x, t3.y, t3.z, t3.w};

  const float* Dbase = D + (size_t)doc * (NUM_WORDS * VEC_DIM) + 2 * lane;
  const float* Wbase = W + 2 * lane;
  const float* Obase = OT + 2 * lane;

  // ---- prefetch all 16 O-rows (L2/L3-hot, coalesced 512B per load) ----
  float2 o[N_TGT];
#pragma unroll
  for (int t = 0; t < N_TGT; ++t)
    o[t] = *(const float2*)(Obase + (size_t)tw[t] * VEC_DIM);

  // ---- gather-sum x = sum_c D[doc, ctx_c] + W[ctx_c] ----
  float2 acc = make_float2(0.f, 0.f);
#pragma unroll
  for (int c = 0; c < N_CTX; ++c) {
    const float2 d = *(const float2*)(Dbase + (size_t)cw[c] * VEC_DIM);
    const float2 w = *(const float2*)(Wbase + (size_t)cw[c] * VEC_DIM);
    acc.x += d.x + w.x;
    acc.y += d.y + w.y;
  }

  // ---- per-lane partials for all 16 targets ----
  float p[N_TGT];
#pragma unroll
  for (int t = 0; t < N_TGT; ++t)
    p[t] = acc.x * o[t].x + acc.y * o[t].y;

  // ---- segmented multi-target reduction ----
  // Stage mask=32: fold targets t / t+8 into lane halves (8 shuffles).
  const bool hi5 = (lane & 32) != 0;
  float q[8];
#pragma unroll
  for (int t = 0; t < 8; ++t) {
    const float send = hi5 ? p[t] : p[t + 8];
    const float recv = __shfl_xor(send, 32, 64);
    const float keep = hi5 ? p[t + 8] : p[t];
    q[t] = keep + recv;
  }
  // Stage mask=16 (4 shuffles).
  const bool hi4 = (lane & 16) != 0;
  float r[4];
#pragma unroll
  for (int t = 0; t < 4; ++t) {
    const float send = hi4 ? q[t] : q[t + 4];
    const float recv = __shfl_xor(send, 16, 64);
    const float keep = hi4 ? q[t + 4] : q[t];
    r[t] = keep + recv;
  }
  // Stage mask=8 (2 shuffles).
  const bool hi3 = (lane & 8) != 0;
  float s2[2];
#pragma unroll
  for (int t = 0; t < 2; ++t) {
    const float send = hi3 ? r[t] : r[t + 2];
    const float recv = __shfl_xor(send, 8, 64);
    const float keep = hi3 ? r[t + 2] : r[t];
    s2[t] = keep + recv;
  }
  // Stage mask=4 (1 shuffle).
  const bool hi2 = (lane & 4) != 0;
  {
    const float send = hi2 ? s2[0] : s2[1];
    const float recv = __shfl_xor(send, 4, 64);
    const float keep = hi2 ? s2[1] : s2[0];
    s2[0] = keep + recv;
  }
  // Finish: sum within each 4-lane segment (2 shuffles).
  float u = s2[0];
  u += __shfl_xor(u, 2, 64);
  u += __shfl_xor(u, 1, 64);

  // Lane l now holds S[(l>>2)&15]; lanes 0,4,...,60 store 16 consecutive floats.
  if ((lane & 3) == 0) out[b * N_TGT + ((lane >> 2) & 15)] = u;
}

extern "C" void kernel_launch(void* const* d_in, const int* in_sizes, int n_in,
                              void* d_out, int out_size, void* d_ws, size_t ws_size,
                              hipStream_t stream) {
  const int*   ctx  = (const int*)d_in[0];    // (4096, 8)
  const int*   docs = (const int*)d_in[1];    // (4096,)
  const int*   tgt  = (const int*)d_in[2];    // (4096, 16)
  const float* D    = (const float*)d_in[3];  // (500, 8000, 128)
  const float* W    = (const float*)d_in[4];  // (8000, 128)
  const float* O    = (const float*)d_in[5];  // (128, 8000)
  float*       out  = (float*)d_out;          // (4096, 16)

  float* OT = (float*)d_ws;  // 4 MB; ws is plenty (harness poisons 8 GB)
  transpose_O_kernel<<<dim3(NUM_WORDS / 32, VEC_DIM / 32), dim3(32, 8), 0, stream>>>(O, OT);
  fused_kernel<<<dim3(BATCH / 4), dim3(256), 0, stream>>>(ctx, docs, tgt, D, W, OT, out);
}

// Round 4
// 20.221 us; speedup vs baseline: 1.0435x; 1.0209x over previous
//
#include <hip/hip_runtime.h>

// Problem constants (from reference)
#define BATCH     4096
#define N_CTX     8
#define N_TGT     16
#define NUM_DOCS  500
#define NUM_WORDS 8000
#define VEC_DIM   128

// ---------------------------------------------------------------------------
// Kernel 1: transpose O (VEC_DIM x NUM_WORDS) -> OT (NUM_WORDS x VEC_DIM)
// so each target word's 128-float vector is contiguous (512 B).
// Known-good from R2.
// ---------------------------------------------------------------------------
__global__ __launch_bounds__(256) void transpose_O_kernel(
    const float* __restrict__ O, float* __restrict__ OT) {
  __shared__ float tile[32][33];  // +1 pad: no bank conflicts
  const int wBase = blockIdx.x * 32;  // word dim (cols of O)
  const int vBase = blockIdx.y * 32;  // vec  dim (rows of O)
  const int tx = threadIdx.x;         // 0..31
  const int ty = threadIdx.y;         // 0..7
#pragma unroll
  for (int i = ty; i < 32; i += 8) {
    tile[i][tx] = O[(size_t)(vBase + i) * NUM_WORDS + (wBase + tx)];
  }
  __syncthreads();
#pragma unroll
  for (int i = ty; i < 32; i += 8) {
    OT[(size_t)(wBase + i) * VEC_DIM + (vBase + tx)] = tile[tx][i];
  }
}

// ---------------------------------------------------------------------------
// Kernel 2: fused gather-sum + 16 dot products.
// One wave serves TWO batches: lanes 0-31 -> b0, lanes 32-63 -> b1.
// Each lane owns a float4 slice (16 B/lane = coalescing sweet spot).
// Per-batch global-load instruction count is half of the R2 version.
// Segmented multi-target reduction: 16 sums per half-wave in 16 shuffles
// total (folds at masks 16/8/4/2 assign target bits, final xor1 sums).
// ---------------------------------------------------------------------------
__global__ __launch_bounds__(256, 2) void fused_kernel(
    const int* __restrict__ ctx, const int* __restrict__ docs,
    const int* __restrict__ tgt, const float* __restrict__ D,
    const float* __restrict__ W, const float* __restrict__ OT,
    float* __restrict__ out) {
  const int wave = threadIdx.x >> 6;
  const int lane = threadIdx.x & 63;
  const int hl   = lane & 31;                         // lane within half
  const int b = (blockIdx.x * 4 + wave) * 2 + (lane >> 5);  // batch per half

  // ---- index loads (uniform within each 32-lane half; 16B broadcasts) ----
  const int4 c0 = *(const int4*)(ctx + b * N_CTX);
  const int4 c1 = *(const int4*)(ctx + b * N_CTX + 4);
  const int  doc = docs[b];
  const int4 t0 = *(const int4*)(tgt + b * N_TGT);
  const int4 t1 = *(const int4*)(tgt + b * N_TGT + 4);
  const int4 t2 = *(const int4*)(tgt + b * N_TGT + 8);
  const int4 t3 = *(const int4*)(tgt + b * N_TGT + 12);
  const int cw[N_CTX] = {c0.x, c0.y, c0.z, c0.w, c1.x, c1.y, c1.z, c1.w};
  const int tw[N_TGT] = {t0.x, t0.y, t0.z, t0.w, t1.x, t1.y, t1.z, t1.w,
                         t2.x, t2.y, t2.z, t2.w, t3.x, t3.y, t3.z, t3.w};

  const float* Dbase = D + (size_t)doc * (NUM_WORDS * VEC_DIM) + 4 * hl;
  const float* Wbase = W + 4 * hl;
  const float* Obase = OT + 4 * hl;

  // ---- prefetch 16 O-rows (512 B contiguous per half-wave, L2/L3-hot) ----
  float4 o[N_TGT];
#pragma unroll
  for (int t = 0; t < N_TGT; ++t)
    o[t] = *(const float4*)(Obase + (size_t)tw[t] * VEC_DIM);

  // ---- gather-sum x = sum_c D[doc, ctx_c] + W[ctx_c] ----
  float4 acc = make_float4(0.f, 0.f, 0.f, 0.f);
#pragma unroll
  for (int c = 0; c < N_CTX; ++c) {
    const float4 d = *(const float4*)(Dbase + (size_t)cw[c] * VEC_DIM);
    const float4 w = *(const float4*)(Wbase + (size_t)cw[c] * VEC_DIM);
    acc.x += d.x + w.x;
    acc.y += d.y + w.y;
    acc.z += d.z + w.z;
    acc.w += d.w + w.w;
  }

  // ---- per-lane partials for all 16 targets ----
  float p[N_TGT];
#pragma unroll
  for (int t = 0; t < N_TGT; ++t)
    p[t] = acc.x * o[t].x + acc.y * o[t].y + acc.z * o[t].z + acc.w * o[t].w;

  // ---- segmented multi-target reduction within each 32-lane half ----
  // Fold mask=16: t-bit3 := lane-bit4 (8 shuffles).
  const bool h4 = (lane & 16) != 0;
  float q[8];
#pragma unroll
  for (int t = 0; t < 8; ++t) {
    const float send = h4 ? p[t] : p[t + 8];
    const float recv = __shfl_xor(send, 16, 64);
    q[t] = (h4 ? p[t + 8] : p[t]) + recv;
  }
  // Fold mask=8: t-bit2 := lane-bit3 (4 shuffles).
  const bool h3 = (lane & 8) != 0;
  float r[4];
#pragma unroll
  for (int t = 0; t < 4; ++t) {
    const float send = h3 ? q[t] : q[t + 4];
    const float recv = __shfl_xor(send, 8, 64);
    r[t] = (h3 ? q[t + 4] : q[t]) + recv;
  }
  // Fold mask=4: t-bit1 := lane-bit2 (2 shuffles).
  const bool h2 = (lane & 4) != 0;
  float s2[2];
#pragma unroll
  for (int t = 0; t < 2; ++t) {
    const float send = h2 ? r[t] : r[t + 2];
    const float recv = __shfl_xor(send, 4, 64);
    s2[t] = (h2 ? r[t + 2] : r[t]) + recv;
  }
  // Fold mask=2: t-bit0 := lane-bit1 (1 shuffle).
  const bool h1 = (lane & 2) != 0;
  float u;
  {
    const float send = h1 ? s2[0] : s2[1];
    const float recv = __shfl_xor(send, 2, 64);
    u = (h1 ? s2[1] : s2[0]) + recv;
  }
  // Final: sum the 2-lane segment (1 shuffle).
  u += __shfl_xor(u, 1, 64);

  // Lane m (within half) holds S[(m>>1)&15]; even lanes store 16 floats
  // per half -> the wave writes two adjacent 64 B output rows.
  if ((lane & 1) == 0) out[b * N_TGT + ((hl >> 1) & 15)] = u;
}

extern "C" void kernel_launch(void* const* d_in, const int* in_sizes, int n_in,
                              void* d_out, int out_size, void* d_ws, size_t ws_size,
                              hipStream_t stream) {
  const int*   ctx  = (const int*)d_in[0];    // (4096, 8)
  const int*   docs = (const int*)d_in[1];    // (4096,)
  const int*   tgt  = (const int*)d_in[2];    // (4096, 16)
  const float* D    = (const float*)d_in[3];  // (500, 8000, 128)
  const float* W    = (const float*)d_in[4];  // (8000, 128)
  const float* O    = (const float*)d_in[5];  // (128, 8000)
  float*       out  = (float*)d_out;          // (4096, 16)

  float* OT = (float*)d_ws;  // 4 MB scratch
  transpose_O_kernel<<<dim3(NUM_WORDS / 32, VEC_DIM / 32), dim3(32, 8), 0, stream>>>(O, OT);
  fused_kernel<<<dim3(BATCH / 8), dim3(256), 0, stream>>>(ctx, docs, tgt, D, W, OT, out);
}

// Round 6
// 19.068 us; speedup vs baseline: 1.1066x; 1.0605x over previous
//
#include <hip/hip_runtime.h>

// Problem constants (from reference)
#define BATCH     4096
#define N_CTX     8
#define N_TGT     16
#define NUM_DOCS  500
#define NUM_WORDS 8000
#define VEC_DIM   128
#define N_TILES   ((NUM_WORDS / 32) * (VEC_DIM / 32))  // 250*4 = 1000

// Native clang vector type: __builtin_nontemporal_load accepts this
// (it rejects HIP_vector_type wrappers like float4).
typedef float floatx4 __attribute__((ext_vector_type(4)));

// ---------------------------------------------------------------------------
// K1: transpose O -> OT  (independent)  ∥  gather-sum x = Σ D[doc,c]+W[c] -> X.
// The transpose LDS work runs under the outstanding D/W gather latency.
// 512 blocks: each transposes 2 of the 1000 32x32 tiles and computes 8 batches.
// ---------------------------------------------------------------------------
__global__ __launch_bounds__(256, 2) void k1_gather_transpose(
    const int* __restrict__ ctx, const int* __restrict__ docs,
    const float* __restrict__ D, const float* __restrict__ W,
    const float* __restrict__ O, float* __restrict__ OT,
    float* __restrict__ X) {
  const int tid  = threadIdx.x;
  const int wave = tid >> 6;
  const int lane = tid & 63;
  const int hl   = lane & 31;
  const int b = (blockIdx.x * 4 + wave) * 2 + (lane >> 5);  // 8 batches/block

  __shared__ float tile[2][32][33];  // +1 pad: conflict-free
  const int tx = tid & 31;
  const int ty = tid >> 5;  // 0..7

  // ---- phase A: issue O-tile loads (independent of everything) ----
  float r[2][4];
  int wB[2], vB[2], tok[2];
#pragma unroll
  for (int s = 0; s < 2; ++s) {
    const int ti = blockIdx.x * 2 + s;  // 0..1023; 1000 real tiles
    tok[s] = (ti < N_TILES);
    wB[s] = (ti % (NUM_WORDS / 32)) * 32;
    vB[s] = (ti / (NUM_WORDS / 32)) * 32;
    if (tok[s]) {
#pragma unroll
      for (int i = 0; i < 4; ++i)
        r[s][i] = O[(size_t)(vB[s] + ty + 8 * i) * NUM_WORDS + (wB[s] + tx)];
    }
  }

  // ---- phase B: issue D/W gather loads into registers ----
  const int4 c0 = *(const int4*)(ctx + b * N_CTX);
  const int4 c1 = *(const int4*)(ctx + b * N_CTX + 4);
  const int  doc = docs[b];
  const int cw[N_CTX] = {c0.x, c0.y, c0.z, c0.w, c1.x, c1.y, c1.z, c1.w};
  const float* Dbase = D + (size_t)doc * (NUM_WORDS * VEC_DIM) + 4 * hl;
  const float* Wbase = W + 4 * hl;
  floatx4 dd[N_CTX], ww[N_CTX];
#pragma unroll
  for (int c = 0; c < N_CTX; ++c) {
    // D has zero reuse (2 GB): nontemporal keeps it from evicting W/O in L2
    dd[c] = __builtin_nontemporal_load(
        (const floatx4*)(Dbase + (size_t)cw[c] * VEC_DIM));
    ww[c] = *(const floatx4*)(Wbase + (size_t)cw[c] * VEC_DIM);
  }

  // ---- phase C: transpose via LDS (overlaps gather latency) ----
#pragma unroll
  for (int s = 0; s < 2; ++s) {
    if (tok[s]) {
#pragma unroll
      for (int i = 0; i < 4; ++i) tile[s][ty + 8 * i][tx] = r[s][i];
    }
  }
  __syncthreads();
#pragma unroll
  for (int s = 0; s < 2; ++s) {
    if (tok[s]) {
#pragma unroll
      for (int i = 0; i < 4; ++i)
        OT[(size_t)(wB[s] + ty + 8 * i) * VEC_DIM + (vB[s] + tx)] =
            tile[s][tx][ty + 8 * i];
    }
  }

  // ---- phase D: accumulate and store X ----
  floatx4 acc = {0.f, 0.f, 0.f, 0.f};
#pragma unroll
  for (int c = 0; c < N_CTX; ++c) acc += dd[c] + ww[c];
  *(floatx4*)(X + (size_t)b * VEC_DIM + 4 * hl) = acc;
}

// ---------------------------------------------------------------------------
// K2: dot phase. One half-wave per batch; lane owns a float4 slice.
// 16 OT rows (contiguous 512 B, L2/L3-hot) + segmented multi-target
// reduction: 16 sums per half in 16 shuffles. Known-good from R4.
// ---------------------------------------------------------------------------
__global__ __launch_bounds__(256, 2) void k2_dot(
    const int* __restrict__ tgt, const float* __restrict__ X,
    const float* __restrict__ OT, float* __restrict__ out) {
  const int wave = threadIdx.x >> 6;
  const int lane = threadIdx.x & 63;
  const int hl   = lane & 31;
  const int b = (blockIdx.x * 4 + wave) * 2 + (lane >> 5);

  const int4 t0 = *(const int4*)(tgt + b * N_TGT);
  const int4 t1 = *(const int4*)(tgt + b * N_TGT + 4);
  const int4 t2 = *(const int4*)(tgt + b * N_TGT + 8);
  const int4 t3 = *(const int4*)(tgt + b * N_TGT + 12);
  const int tw[N_TGT] = {t0.x, t0.y, t0.z, t0.w, t1.x, t1.y, t1.z, t1.w,
                         t2.x, t2.y, t2.z, t2.w, t3.x, t3.y, t3.z, t3.w};

  const float* Obase = OT + 4 * hl;
  floatx4 o[N_TGT];
#pragma unroll
  for (int t = 0; t < N_TGT; ++t)
    o[t] = *(const floatx4*)(Obase + (size_t)tw[t] * VEC_DIM);

  const floatx4 xv = *(const floatx4*)(X + (size_t)b * VEC_DIM + 4 * hl);

  float p[N_TGT];
#pragma unroll
  for (int t = 0; t < N_TGT; ++t) {
    const floatx4 m = xv * o[t];
    p[t] = m.x + m.y + m.z + m.w;
  }

  // segmented multi-target reduction within each 32-lane half
  const bool h4 = (lane & 16) != 0;
  float q[8];
#pragma unroll
  for (int t = 0; t < 8; ++t) {
    const float send = h4 ? p[t] : p[t + 8];
    const float recv = __shfl_xor(send, 16, 64);
    q[t] = (h4 ? p[t + 8] : p[t]) + recv;
  }
  const bool h3 = (lane & 8) != 0;
  float rr[4];
#pragma unroll
  for (int t = 0; t < 4; ++t) {
    const float send = h3 ? q[t] : q[t + 4];
    const float recv = __shfl_xor(send, 8, 64);
    rr[t] = (h3 ? q[t + 4] : q[t]) + recv;
  }
  const bool h2 = (lane & 4) != 0;
  float s2[2];
#pragma unroll
  for (int t = 0; t < 2; ++t) {
    const float send = h2 ? rr[t] : rr[t + 2];
    const float recv = __shfl_xor(send, 4, 64);
    s2[t] = (h2 ? rr[t + 2] : rr[t]) + recv;
  }
  const bool h1 = (lane & 2) != 0;
  float u;
  {
    const float send = h1 ? s2[0] : s2[1];
    const float recv = __shfl_xor(send, 2, 64);
    u = (h1 ? s2[1] : s2[0]) + recv;
  }
  u += __shfl_xor(u, 1, 64);

  if ((lane & 1) == 0) out[b * N_TGT + ((hl >> 1) & 15)] = u;
}

extern "C" void kernel_launch(void* const* d_in, const int* in_sizes, int n_in,
                              void* d_out, int out_size, void* d_ws, size_t ws_size,
                              hipStream_t stream) {
  const int*   ctx  = (const int*)d_in[0];    // (4096, 8)
  const int*   docs = (const int*)d_in[1];    // (4096,)
  const int*   tgt  = (const int*)d_in[2];    // (4096, 16)
  const float* D    = (const float*)d_in[3];  // (500, 8000, 128)
  const float* W    = (const float*)d_in[4];  // (8000, 128)
  const float* O    = (const float*)d_in[5];  // (128, 8000)
  float*       out  = (float*)d_out;          // (4096, 16)

  float* OT = (float*)d_ws;                                   // 4 MB
  float* X  = (float*)d_ws + (size_t)NUM_WORDS * VEC_DIM;     // 2 MB

  k1_gather_transpose<<<dim3(BATCH / 8), dim3(256), 0, stream>>>(
      ctx, docs, D, W, O, OT, X);
  k2_dot<<<dim3(BATCH / 8), dim3(256), 0, stream>>>(tgt, X, OT, out);
}